// Round 3
// baseline (389.962 us; speedup 1.0000x reference)
//
#include <hip/hip_runtime.h>

// N=524288 rows, K=128, outd=256 cols, num_grid=255
#define M_TOTAL     524288
#define KDIM        128
#define NCOL        256
#define NITER       (M_TOTAL / 32)     // 16384 iterations of 32 rows
#define GRID_BLOCKS 2048
#define IPB         (NITER / GRID_BLOCKS)   // 8 iterations per block, exact
#define LOG2E       1.44269504088896340736f

typedef _Float16 half8   __attribute__((ext_vector_type(8)));
typedef float    floatx4 __attribute__((ext_vector_type(4)));

// DPP prefix-sum within each 16-lane group (VALU pipe, no DS traffic).
template <int CTRL>
__device__ __forceinline__ float dpp_add_step(float x) {
    int xi = __builtin_bit_cast(int, x);
    int sh = __builtin_amdgcn_update_dpp(0, xi, CTRL, 0xF, 0xF, true);
    return x + __builtin_bit_cast(float, sh);
}
__device__ __forceinline__ float row16_sum(float x) {
    x = dpp_add_step<0x111>(x);  // row_shr:1
    x = dpp_add_step<0x112>(x);  // row_shr:2
    x = dpp_add_step<0x114>(x);  // row_shr:4
    x = dpp_add_step<0x118>(x);  // row_shr:8
    return x;
}

// fp32 -> (hi,lo) fp16 2-pass split for 16 consecutive floats.
__device__ __forceinline__ void cvt16(const floatx4 pf[4],
                                      half8& h0, half8& h1, half8& l0, half8& l1) {
    const float* f = (const float*)pf;
    #pragma unroll
    for (int j = 0; j < 8; ++j) {
        float a = f[j];
        _Float16 h = (_Float16)a;
        h0[j] = h;
        l0[j] = (_Float16)(a - (float)h);
    }
    #pragma unroll
    for (int j = 0; j < 8; ++j) {
        float a = f[8 + j];
        _Float16 h = (_Float16)a;
        h1[j] = h;
        l1[j] = (_Float16)(a - (float)h);
    }
}

// waves_per_eu(1,4): R3 change. At (2,4) the allocator squeezed to 80 arch-VGPRs
// while ~150 values want to be live (pf prefetch, frags, bfrag, acc) -> schedule
// likely sinks global-load issue toward its consumer, re-exposing HBM latency
// each iteration. min=1 gives the allocator a 512-reg budget; natural pressure
// should settle ~120-170 -> 2-3 waves/EU with a deep schedule.
__global__ __attribute__((amdgpu_flat_work_group_size(256, 256), amdgpu_waves_per_eu(1, 4)))
void density_kernel(const float* __restrict__ t,
                    const float* __restrict__ x,
                    const float* __restrict__ w,     // [128][256] row-major
                    const float* __restrict__ bias,  // [256]
                    float* __restrict__ out)
{
    // per-wave partials: [parity][subtile][row-in-16][wave] = (denom, numer)
    __shared__ alignas(16) float2 part[2][2][16][4];
    // double-buffered hi/lo fp16 A-tile, chunk-XOR-swizzled:
    // element A[row][k] lives at tHi[p][row][(k>>3 ^ (row&7))*8 + (k&7)]
    __shared__ alignas(16) _Float16 tHi[2][32][128];
    __shared__ alignas(16) _Float16 tLo[2][32][128];

    const int tid  = threadIdx.x;
    const int wave = tid >> 6;        // 0..3, owns cols [wave*64, wave*64+64)
    const int lane = tid & 63;
    const int n    = lane & 15;       // col-in-16 (B/C) == row-in-16 (A)
    const int q    = lane >> 4;       // quad selector
    const int colbase = wave * 64;

    // ---- B fragments resident in VGPRs for the whole kernel.
    // fp16(W * log2e): exp(logit) == exp2(logit') with logits' = A@(W*log2e) + b*log2e.
    half8 bfrag[4][4];   // [coltile][kstep]
    float biasv[4], colf[4];
    #pragma unroll
    for (int ct = 0; ct < 4; ++ct) {
        const int col = colbase + ct * 16 + n;
        #pragma unroll
        for (int ks = 0; ks < 4; ++ks) {
            const int k0 = ks * 32 + q * 8;
            half8 b;
            #pragma unroll
            for (int j = 0; j < 8; ++j)
                b[j] = (_Float16)(w[(k0 + j) * NCOL + col] * LOG2E);
            bfrag[ct][ks] = b;
        }
        biasv[ct] = bias[col] * LOG2E;
        colf[ct]  = (float)col;
    }

    // ---- staging geometry: thread covers row sr, k in [sm*16, sm*16+16)
    const int sr  = tid >> 3;          // 0..31
    const int sm  = tid & 7;           // 0..7
    const int c0s = ((2 * sm)     ^ (sr & 7)) * 8;   // swizzled chunk offsets (halves)
    const int c1s = ((2 * sm + 1) ^ (sr & 7)) * 8;

    // fragment-read swizzled chunk offsets: chunk(ks) = ks*4+q -> ^(row&7) = ^(n&7)
    int rdc[4];
    #pragma unroll
    for (int ks = 0; ks < 4; ++ks) rdc[ks] = (((ks * 4 + q) ^ (n & 7)) * 8);

    // ---- prologue: stage tile(it=blockIdx.x) + its t values
    floatx4 tvA, tvB;
    {
        const int it0 = blockIdx.x;
        const float* src = x + (size_t)it0 * (32 * KDIM) + tid * 16;
        floatx4 pf[4];
        pf[0] = ((const floatx4*)src)[0];
        pf[1] = ((const floatx4*)src)[1];
        pf[2] = ((const floatx4*)src)[2];
        pf[3] = ((const floatx4*)src)[3];
        tvA = *(const floatx4*)(t + it0 * 32 + q * 4);
        tvB = *(const floatx4*)(t + it0 * 32 + 16 + q * 4);
        half8 h0, h1, l0, l1;
        cvt16(pf, h0, h1, l0, l1);
        *(half8*)&tHi[0][sr][c0s] = h0;
        *(half8*)&tHi[0][sr][c1s] = h1;
        *(half8*)&tLo[0][sr][c0s] = l0;
        *(half8*)&tLo[0][sr][c1s] = l1;
    }
    __syncthreads();

    int p = 0;
    #pragma unroll 1
    for (int ii = 0; ii < IPB; ++ii) {
        const int it   = blockIdx.x + ii * GRID_BLOCKS;
        const int row0 = it * 32;
        const int itn  = (ii + 1 < IPB) ? it + GRID_BLOCKS : it;  // last iter: dummy reload

        // ---- issue next tile's global loads NOW; consumed after the epilogue
        floatx4 pf[4];
        {
            const float* src = x + (size_t)itn * (32 * KDIM) + tid * 16;
            pf[0] = ((const floatx4*)src)[0];
            pf[1] = ((const floatx4*)src)[1];
            pf[2] = ((const floatx4*)src)[2];
            pf[3] = ((const floatx4*)src)[3];
        }
        const floatx4 tvAn = *(const floatx4*)(t + itn * 32 + q * 4);
        const floatx4 tvBn = *(const floatx4*)(t + itn * 32 + 16 + q * 4);

        // ---- A fragments from LDS (conflict-free via XOR swizzle)
        const _Float16* hiA = &tHi[p][n][0];
        const _Float16* loA = &tLo[p][n][0];
        const _Float16* hiB = &tHi[p][16 + n][0];
        const _Float16* loB = &tLo[p][16 + n][0];
        half8 ahiA[4], aloA[4], ahiB[4], aloB[4];
        #pragma unroll
        for (int ks = 0; ks < 4; ++ks) {
            ahiA[ks] = *(const half8*)&hiA[rdc[ks]];
            aloA[ks] = *(const half8*)&loA[rdc[ks]];
            ahiB[ks] = *(const half8*)&hiB[rdc[ks]];
            aloB[ks] = *(const half8*)&loB[rdc[ks]];
        }

        // ---- MFMA, fp16 2-pass (setprio: T5 — waves are phase-skewed, let
        // MFMA-entering waves win issue arbitration over epilogue-phase waves)
        floatx4 accA[4], accB[4];
        #pragma unroll
        for (int ct = 0; ct < 4; ++ct) {
            accA[ct] = (floatx4){biasv[ct], biasv[ct], biasv[ct], biasv[ct]};
            accB[ct] = accA[ct];
        }
        __builtin_amdgcn_s_setprio(1);
        #pragma unroll
        for (int ks = 0; ks < 4; ++ks) {
            #pragma unroll
            for (int ct = 0; ct < 4; ++ct) {
                accA[ct] = __builtin_amdgcn_mfma_f32_16x16x32_f16(ahiA[ks], bfrag[ct][ks], accA[ct], 0, 0, 0);
                accA[ct] = __builtin_amdgcn_mfma_f32_16x16x32_f16(aloA[ks], bfrag[ct][ks], accA[ct], 0, 0, 0);
            }
        }
        #pragma unroll
        for (int ks = 0; ks < 4; ++ks) {
            #pragma unroll
            for (int ct = 0; ct < 4; ++ct) {
                accB[ct] = __builtin_amdgcn_mfma_f32_16x16x32_f16(ahiB[ks], bfrag[ct][ks], accB[ct], 0, 0, 0);
                accB[ct] = __builtin_amdgcn_mfma_f32_16x16x32_f16(aloB[ks], bfrag[ct][ks], accB[ct], 0, 0, 0);
            }
        }
        __builtin_amdgcn_s_setprio(0);

        // ---- fused epilogues (hat-function interp; |logit| small, no max-sub)
        float tgA[4], tgB[4];
        #pragma unroll
        for (int r = 0; r < 4; ++r) { tgA[r] = tvA[r] * 255.0f; tgB[r] = tvB[r] * 255.0f; }
        float sA[4] = {0,0,0,0}, nmA[4] = {0,0,0,0};
        float sB[4] = {0,0,0,0}, nmB[4] = {0,0,0,0};
        #pragma unroll
        for (int ct = 0; ct < 4; ++ct) {
            #pragma unroll
            for (int r = 0; r < 4; ++r) {
                float eA = __builtin_amdgcn_exp2f(accA[ct][r]);
                float eB = __builtin_amdgcn_exp2f(accB[ct][r]);
                sA[r] += eA;
                sB[r] += eB;
                float wA = fmaxf(0.0f, 1.0f - fabsf(colf[ct] - tgA[r]));
                float wB = fmaxf(0.0f, 1.0f - fabsf(colf[ct] - tgB[r]));
                nmA[r] = fmaf(eA, wA, nmA[r]);
                nmB[r] = fmaf(eB, wB, nmB[r]);
            }
        }

        // ---- 16-lane reductions on the VALU pipe
        #pragma unroll
        for (int r = 0; r < 4; ++r) {
            sA[r]  = row16_sum(sA[r]);
            nmA[r] = row16_sum(nmA[r]);
            sB[r]  = row16_sum(sB[r]);
            nmB[r] = row16_sum(nmB[r]);
        }

        if (n == 15) {
            #pragma unroll
            for (int r = 0; r < 4; ++r) {
                part[p][0][q * 4 + r][wave] = make_float2(sA[r], nmA[r]);
                part[p][1][q * 4 + r][wave] = make_float2(sB[r], nmB[r]);
            }
        }

        // ---- convert + publish next tile (vmcnt wait lands here, latency hidden)
        {
            half8 h0, h1, l0, l1;
            cvt16(pf, h0, h1, l0, l1);
            const int pn = p ^ 1;
            *(half8*)&tHi[pn][sr][c0s] = h0;
            *(half8*)&tHi[pn][sr][c1s] = h1;
            *(half8*)&tLo[pn][sr][c0s] = l0;
            *(half8*)&tLo[pn][sr][c1s] = l1;
        }
        __syncthreads();

        // ---- combine 4 wave-partials per row, store 32 outputs
        if (tid < 32) {
            const int st = tid >> 4, r = tid & 15;
            const float4* pr = (const float4*)&part[p][st][r][0];
            float4 a = pr[0], b = pr[1];
            float s  = a.x + a.z + b.x + b.z;
            float nm = a.y + a.w + b.y + b.w;
            out[row0 + tid] = nm / s;
        }
        tvA = tvAn;
        tvB = tvBn;
        p ^= 1;  // flips both the tile and part parities
    }
}

extern "C" void kernel_launch(void* const* d_in, const int* in_sizes, int n_in,
                              void* d_out, int out_size, void* d_ws, size_t ws_size,
                              hipStream_t stream) {
    const float* t    = (const float*)d_in[0];
    const float* x    = (const float*)d_in[1];
    const float* wgt  = (const float*)d_in[2];
    const float* bias = (const float*)d_in[3];
    float* out = (float*)d_out;

    density_kernel<<<GRID_BLOCKS, 256, 0, stream>>>(t, x, wgt, bias, out);
}

// Round 4
// 380.178 us; speedup vs baseline: 1.0257x; 1.0257x over previous
//
#include <hip/hip_runtime.h>

// N=524288 rows, K=128, outd=256 cols, num_grid=255
#define M_TOTAL     524288
#define KDIM        128
#define NCOL        256
#define NITER       (M_TOTAL / 32)     // 16384 iterations of 32 rows
#define GRID_BLOCKS 1024               // R4: exactly 4 blocks/CU resident (LDS 34.25KB -> 4 fit)
#define IPB         (NITER / GRID_BLOCKS)   // 16 iterations per block, exact
#define LOG2E       1.44269504088896340736f

typedef _Float16 half8   __attribute__((ext_vector_type(8)));
typedef float    floatx4 __attribute__((ext_vector_type(4)));

// DPP prefix-sum within each 16-lane group (VALU pipe, no DS traffic).
template <int CTRL>
__device__ __forceinline__ float dpp_add_step(float x) {
    int xi = __builtin_bit_cast(int, x);
    int sh = __builtin_amdgcn_update_dpp(0, xi, CTRL, 0xF, 0xF, true);
    return x + __builtin_bit_cast(float, sh);
}
__device__ __forceinline__ float row16_sum(float x) {
    x = dpp_add_step<0x111>(x);  // row_shr:1
    x = dpp_add_step<0x112>(x);  // row_shr:2
    x = dpp_add_step<0x114>(x);  // row_shr:4
    x = dpp_add_step<0x118>(x);  // row_shr:8
    return x;
}

// fp32 -> (hi,lo) fp16 2-pass split for 16 consecutive floats. (Numerics frozen:
// absmax sits exactly at 0.00390625; don't perturb rounding until tolerance
// headroom is known.)
__device__ __forceinline__ void cvt16(const floatx4 pf[4],
                                      half8& h0, half8& h1, half8& l0, half8& l1) {
    const float* f = (const float*)pf;
    #pragma unroll
    for (int j = 0; j < 8; ++j) {
        float a = f[j];
        _Float16 h = (_Float16)a;
        h0[j] = h;
        l0[j] = (_Float16)(a - (float)h);
    }
    #pragma unroll
    for (int j = 0; j < 8; ++j) {
        float a = f[8 + j];
        _Float16 h = (_Float16)a;
        h1[j] = h;
        l1[j] = (_Float16)(a - (float)h);
    }
}

// waves_per_eu(2,4): R2's proven config (R3's (1,4)+setprio bundle regressed;
// true unified reg usage ~176 incl. AGPRs -> ~2.9 waves/SIMD either way, and
// setprio hurts in this barrier-lockstep structure, cf. m190).
__global__ __attribute__((amdgpu_flat_work_group_size(256, 256), amdgpu_waves_per_eu(2, 4)))
void density_kernel(const float* __restrict__ t,
                    const float* __restrict__ x,
                    const float* __restrict__ w,     // [128][256] row-major
                    const float* __restrict__ bias,  // [256]
                    float* __restrict__ out)
{
    // per-wave partials: [parity][subtile][row-in-16][wave] = (denom, numer)
    __shared__ alignas(16) float2 part[2][2][16][4];
    // double-buffered hi/lo fp16 A-tile, chunk-XOR-swizzled:
    // element A[row][k] lives at tHi[p][row][(k>>3 ^ (row&7))*8 + (k&7)]
    __shared__ alignas(16) _Float16 tHi[2][32][128];
    __shared__ alignas(16) _Float16 tLo[2][32][128];

    const int tid  = threadIdx.x;
    const int wave = tid >> 6;        // 0..3, owns cols [wave*64, wave*64+64)
    const int lane = tid & 63;
    const int n    = lane & 15;       // col-in-16 (B/C) == row-in-16 (A)
    const int q    = lane >> 4;       // quad selector
    const int colbase = wave * 64;

    // ---- B fragments resident in VGPRs/AGPRs for the whole kernel.
    // fp16(W * log2e): exp(logit) == exp2(logit') with logits' = A@(W*log2e) + b*log2e.
    half8 bfrag[4][4];   // [coltile][kstep]
    float biasv[4], colf[4];
    #pragma unroll
    for (int ct = 0; ct < 4; ++ct) {
        const int col = colbase + ct * 16 + n;
        #pragma unroll
        for (int ks = 0; ks < 4; ++ks) {
            const int k0 = ks * 32 + q * 8;
            half8 b;
            #pragma unroll
            for (int j = 0; j < 8; ++j)
                b[j] = (_Float16)(w[(k0 + j) * NCOL + col] * LOG2E);
            bfrag[ct][ks] = b;
        }
        biasv[ct] = bias[col] * LOG2E;
        colf[ct]  = (float)col;
    }

    // ---- staging geometry: thread covers row sr, k in [sm*16, sm*16+16)
    const int sr  = tid >> 3;          // 0..31
    const int sm  = tid & 7;           // 0..7
    const int c0s = ((2 * sm)     ^ (sr & 7)) * 8;   // swizzled chunk offsets (halves)
    const int c1s = ((2 * sm + 1) ^ (sr & 7)) * 8;

    // fragment-read swizzled chunk offsets: chunk(ks) = ks*4+q -> ^(row&7) = ^(n&7)
    int rdc[4];
    #pragma unroll
    for (int ks = 0; ks < 4; ++ks) rdc[ks] = (((ks * 4 + q) ^ (n & 7)) * 8);

    // ---- R4: strength-reduced addressing — scalar pointer bumps per iteration.
    const size_t X_STRIDE = (size_t)GRID_BLOCKS * 32 * KDIM;   // floats
    const int    T_STRIDE = GRID_BLOCKS * 32;
    const float* srcX = x + (size_t)blockIdx.x * (32 * KDIM) + tid * 16;
    const float* srcT = t + blockIdx.x * 32;
    float*       outP = out + blockIdx.x * 32;

    // ---- prologue: stage tile(it=blockIdx.x) + its t values
    floatx4 tvA, tvB;
    {
        floatx4 pf[4];
        pf[0] = ((const floatx4*)srcX)[0];
        pf[1] = ((const floatx4*)srcX)[1];
        pf[2] = ((const floatx4*)srcX)[2];
        pf[3] = ((const floatx4*)srcX)[3];
        tvA = *(const floatx4*)(srcT + q * 4);
        tvB = *(const floatx4*)(srcT + 16 + q * 4);
        half8 h0, h1, l0, l1;
        cvt16(pf, h0, h1, l0, l1);
        *(half8*)&tHi[0][sr][c0s] = h0;
        *(half8*)&tHi[0][sr][c1s] = h1;
        *(half8*)&tLo[0][sr][c0s] = l0;
        *(half8*)&tLo[0][sr][c1s] = l1;
    }
    __syncthreads();

    int p = 0;
    #pragma unroll 1
    for (int ii = 0; ii < IPB; ++ii) {
        // ---- issue next tile's global loads NOW; consumed after the epilogue.
        // Last iteration: re-load current tile (dummy, keeps control flow uniform).
        const size_t xadv = (ii + 1 < IPB) ? X_STRIDE : 0;
        const int    tadv = (ii + 1 < IPB) ? T_STRIDE : 0;
        const float* ldX = srcX + xadv;
        const float* ldT = srcT + tadv;
        floatx4 pf[4];
        pf[0] = ((const floatx4*)ldX)[0];
        pf[1] = ((const floatx4*)ldX)[1];
        pf[2] = ((const floatx4*)ldX)[2];
        pf[3] = ((const floatx4*)ldX)[3];
        const floatx4 tvAn = *(const floatx4*)(ldT + q * 4);
        const floatx4 tvBn = *(const floatx4*)(ldT + 16 + q * 4);

        // ---- A fragments from LDS (conflict-free via XOR swizzle)
        const _Float16* hiA = &tHi[p][n][0];
        const _Float16* loA = &tLo[p][n][0];
        const _Float16* hiB = &tHi[p][16 + n][0];
        const _Float16* loB = &tLo[p][16 + n][0];
        half8 ahiA[4], aloA[4], ahiB[4], aloB[4];
        #pragma unroll
        for (int ks = 0; ks < 4; ++ks) {
            ahiA[ks] = *(const half8*)&hiA[rdc[ks]];
            aloA[ks] = *(const half8*)&loA[rdc[ks]];
            ahiB[ks] = *(const half8*)&hiB[rdc[ks]];
            aloB[ks] = *(const half8*)&loB[rdc[ks]];
        }

        // ---- MFMA, fp16 2-pass
        floatx4 accA[4], accB[4];
        #pragma unroll
        for (int ct = 0; ct < 4; ++ct) {
            accA[ct] = (floatx4){biasv[ct], biasv[ct], biasv[ct], biasv[ct]};
            accB[ct] = accA[ct];
        }
        #pragma unroll
        for (int ks = 0; ks < 4; ++ks) {
            #pragma unroll
            for (int ct = 0; ct < 4; ++ct) {
                accA[ct] = __builtin_amdgcn_mfma_f32_16x16x32_f16(ahiA[ks], bfrag[ct][ks], accA[ct], 0, 0, 0);
                accA[ct] = __builtin_amdgcn_mfma_f32_16x16x32_f16(aloA[ks], bfrag[ct][ks], accA[ct], 0, 0, 0);
            }
        }
        #pragma unroll
        for (int ks = 0; ks < 4; ++ks) {
            #pragma unroll
            for (int ct = 0; ct < 4; ++ct) {
                accB[ct] = __builtin_amdgcn_mfma_f32_16x16x32_f16(ahiB[ks], bfrag[ct][ks], accB[ct], 0, 0, 0);
                accB[ct] = __builtin_amdgcn_mfma_f32_16x16x32_f16(aloB[ks], bfrag[ct][ks], accB[ct], 0, 0, 0);
            }
        }

        // ---- fused epilogues (hat-function interp; |logit| small, no max-sub)
        float tgA[4], tgB[4];
        #pragma unroll
        for (int r = 0; r < 4; ++r) { tgA[r] = tvA[r] * 255.0f; tgB[r] = tvB[r] * 255.0f; }
        float sA[4] = {0,0,0,0}, nmA[4] = {0,0,0,0};
        float sB[4] = {0,0,0,0}, nmB[4] = {0,0,0,0};
        #pragma unroll
        for (int ct = 0; ct < 4; ++ct) {
            #pragma unroll
            for (int r = 0; r < 4; ++r) {
                float eA = __builtin_amdgcn_exp2f(accA[ct][r]);
                float eB = __builtin_amdgcn_exp2f(accB[ct][r]);
                sA[r] += eA;
                sB[r] += eB;
                float wA = fmaxf(0.0f, 1.0f - fabsf(colf[ct] - tgA[r]));
                float wB = fmaxf(0.0f, 1.0f - fabsf(colf[ct] - tgB[r]));
                nmA[r] = fmaf(eA, wA, nmA[r]);
                nmB[r] = fmaf(eB, wB, nmB[r]);
            }
        }

        // ---- 16-lane reductions on the VALU pipe
        #pragma unroll
        for (int r = 0; r < 4; ++r) {
            sA[r]  = row16_sum(sA[r]);
            nmA[r] = row16_sum(nmA[r]);
            sB[r]  = row16_sum(sB[r]);
            nmB[r] = row16_sum(nmB[r]);
        }

        if (n == 15) {
            #pragma unroll
            for (int r = 0; r < 4; ++r) {
                part[p][0][q * 4 + r][wave] = make_float2(sA[r], nmA[r]);
                part[p][1][q * 4 + r][wave] = make_float2(sB[r], nmB[r]);
            }
        }

        // ---- convert + publish next tile (vmcnt wait lands here, latency hidden)
        {
            half8 h0, h1, l0, l1;
            cvt16(pf, h0, h1, l0, l1);
            const int pn = p ^ 1;
            *(half8*)&tHi[pn][sr][c0s] = h0;
            *(half8*)&tHi[pn][sr][c1s] = h1;
            *(half8*)&tLo[pn][sr][c0s] = l0;
            *(half8*)&tLo[pn][sr][c1s] = l1;
        }
        __syncthreads();

        // ---- combine 4 wave-partials per row, store 32 outputs
        if (tid < 32) {
            const int st = tid >> 4, r = tid & 15;
            const float4* pr = (const float4*)&part[p][st][r][0];
            float4 a = pr[0], b = pr[1];
            float s  = a.x + a.z + b.x + b.z;
            float nm = a.y + a.w + b.y + b.w;
            outP[tid] = nm / s;
        }
        srcX += xadv;
        srcT  = ldT;
        outP += T_STRIDE;
        tvA = tvAn;
        tvB = tvBn;
        p ^= 1;  // flips both the tile and part parities
    }
}

extern "C" void kernel_launch(void* const* d_in, const int* in_sizes, int n_in,
                              void* d_out, int out_size, void* d_ws, size_t ws_size,
                              hipStream_t stream) {
    const float* t    = (const float*)d_in[0];
    const float* x    = (const float*)d_in[1];
    const float* wgt  = (const float*)d_in[2];
    const float* bias = (const float*)d_in[3];
    float* out = (float*)d_out;

    density_kernel<<<GRID_BLOCKS, 256, 0, stream>>>(t, x, wgt, bias, out);
}